// Round 1
// baseline (1188.851 us; speedup 1.0000x reference)
//
#include <hip/hip_runtime.h>

#define N_NODES 10000
#define N_EDGES 640000
#define D 128

// ---------------------------------------------------------------------------
// Kernel 1: zero the h accumulator in workspace (ws is re-poisoned to 0xAA
// before every timed launch, so we must zero it ourselves each call).
// ---------------------------------------------------------------------------
__global__ __launch_bounds__(256) void zero_kernel(float* __restrict__ p, int n) {
    int i = blockIdx.x * 256 + threadIdx.x;
    if (i < n) p[i] = 0.0f;
}

// ---------------------------------------------------------------------------
// Kernel 2: edge-parallel gather + scatter-add.
// 32 threads per edge, each thread handles 4 contiguous columns (float4 load
// from x[src[e]], 4 atomicAdds into h[dst[e]]).
// ---------------------------------------------------------------------------
__global__ __launch_bounds__(256) void scatter_kernel(
    const float4* __restrict__ x4,   // x viewed as [N_NODES][32] float4
    const int* __restrict__ src,
    const int* __restrict__ dst,
    float* __restrict__ h) {
    int gid = blockIdx.x * 256 + threadIdx.x;
    int e = gid >> 5;                // 32 threads per edge
    if (e >= N_EDGES) return;
    int c = gid & 31;                // float4 index within the row

    int s = src[e];
    int d = dst[e];
    float4 v = x4[s * 32 + c];       // coalesced across the 32 threads of an edge
    float* hp = h + d * D + c * 4;
    atomicAdd(hp + 0, v.x);
    atomicAdd(hp + 1, v.y);
    atomicAdd(hp + 2, v.z);
    atomicAdd(hp + 3, v.w);
}

// ---------------------------------------------------------------------------
// Kernel 3: out[n][o] = b[o] + sum_k h[n][k] * W[o][k]
// Block = 128 threads, thread t computes column t for NPB nodes.
// W staged in LDS with skewed layout addr(k,t) = k*128 + ((t+k)&127) holding
// W[t][k]:
//   - transpose write: thread t writes bank (o+t)%32 -> 2-way aliasing (free)
//   - read at (k,t):   thread t reads bank (t+k)%32  -> 2-way aliasing (free)
// h[n][k] reads are wave-uniform -> scalar cache broadcast.
// ---------------------------------------------------------------------------
#define NPB 32
__global__ __launch_bounds__(128) void gemm_kernel(
    const float* __restrict__ h,
    const float* __restrict__ W,
    const float* __restrict__ b,
    float* __restrict__ out) {
    __shared__ float Ws[D * D];      // 64 KB, skewed

    int t = threadIdx.x;             // 0..127 = output column
    // Stage W transposed+skewed. Global reads coalesced (threads sweep k=t).
    #pragma unroll 4
    for (int o = 0; o < D; ++o) {
        Ws[t * D + ((o + t) & (D - 1))] = W[o * D + t];
    }
    __syncthreads();

    float bt = b[t];
    int n0 = blockIdx.x * NPB;

    for (int ng = 0; ng < NPB; ng += 8) {
        float acc[8];
        #pragma unroll
        for (int j = 0; j < 8; ++j) acc[j] = bt;

        // clamp row indices so the last partial block stays in-bounds
        const float* hp[8];
        #pragma unroll
        for (int j = 0; j < 8; ++j) {
            int n = n0 + ng + j;
            int nc = n < N_NODES ? n : (N_NODES - 1);
            hp[j] = h + nc * D;
        }

        #pragma unroll 4
        for (int k = 0; k < D; ++k) {
            float w = Ws[k * D + ((t + k) & (D - 1))];
            #pragma unroll
            for (int j = 0; j < 8; ++j) acc[j] += hp[j][k] * w;
        }

        #pragma unroll
        for (int j = 0; j < 8; ++j) {
            int n = n0 + ng + j;
            if (n < N_NODES) out[n * D + t] = acc[j];
        }
    }
}

// ---------------------------------------------------------------------------
extern "C" void kernel_launch(void* const* d_in, const int* in_sizes, int n_in,
                              void* d_out, int out_size, void* d_ws, size_t ws_size,
                              hipStream_t stream) {
    const float* x   = (const float*)d_in[0];   // [10000,128] fp32
    const int*   src = (const int*)  d_in[1];   // [640000]
    const int*   dst = (const int*)  d_in[2];   // [640000]
    const float* W   = (const float*)d_in[3];   // [128,128] fp32
    const float* b   = (const float*)d_in[4];   // [128]
    float* out = (float*)d_out;                 // [10000,128] fp32
    float* h   = (float*)d_ws;                  // 5.12 MB accumulator in ws

    const int hN = N_NODES * D;

    // 1) zero h
    zero_kernel<<<(hN + 255) / 256, 256, 0, stream>>>(h, hN);

    // 2) scatter-add: 32 threads/edge
    {
        long total = (long)N_EDGES * 32;
        int blocks = (int)((total + 255) / 256);
        scatter_kernel<<<blocks, 256, 0, stream>>>((const float4*)x, src, dst, h);
    }

    // 3) out = h @ W.T + b
    {
        int blocks = (N_NODES + NPB - 1) / NPB;
        gemm_kernel<<<blocks, 128, 0, stream>>>(h, W, b, out);
    }
}

// Round 2
// 264.176 us; speedup vs baseline: 4.5002x; 4.5002x over previous
//
#include <hip/hip_runtime.h>

#define N_NODES 10000
#define N_EDGES 640000
#define D 128

// ws layout (ints): edge_src[640000] | row_start[10001] | cursor[10001] | counts[10000]
#define WS_EDGE_SRC 0
#define WS_ROWSTART 640000
#define WS_CURSOR   650016
#define WS_COUNTS   660032
// total 670032 ints = 2.68 MB

// ---------------------------------------------------------------------------
__global__ __launch_bounds__(256) void zero_counts_kernel(int* __restrict__ counts) {
    int i = blockIdx.x * 256 + threadIdx.x;
    if (i < N_NODES) counts[i] = 0;
}

// ---------------------------------------------------------------------------
// Histogram of dst: 640K int atomics on a 40 KB L2-hot array.
__global__ __launch_bounds__(256) void hist_kernel(const int* __restrict__ dst,
                                                   int* __restrict__ counts) {
    int e = blockIdx.x * 256 + threadIdx.x;
    if (e < N_EDGES) atomicAdd(&counts[dst[e]], 1);
}

// ---------------------------------------------------------------------------
// Single-block exclusive scan over 10000 counts -> row_start[0..10000], and a
// working copy in cursor[] for the scatter pass. 1024 threads x 10 elems each.
__global__ __launch_bounds__(1024) void scan_kernel(const int* __restrict__ counts,
                                                    int* __restrict__ row_start,
                                                    int* __restrict__ cursor) {
    __shared__ int part[1024];
    int t = threadIdx.x;
    int base = t * 10;
    int local[10];
    int s = 0;
    #pragma unroll
    for (int i = 0; i < 10; ++i) {
        int idx = base + i;
        int c = (idx < N_NODES) ? counts[idx] : 0;
        local[i] = s;           // exclusive within chunk
        s += c;
    }
    part[t] = s;
    __syncthreads();
    // Hillis-Steele inclusive scan of the 1024 partials
    for (int off = 1; off < 1024; off <<= 1) {
        int v = (t >= off) ? part[t - off] : 0;
        __syncthreads();
        part[t] += v;
        __syncthreads();
    }
    int pre = (t > 0) ? part[t - 1] : 0;
    #pragma unroll
    for (int i = 0; i < 10; ++i) {
        int idx = base + i;
        if (idx < N_NODES) {
            int st = pre + local[i];
            row_start[idx] = st;
            cursor[idx] = st;
        }
    }
    if (t == 1023) {
        row_start[N_NODES] = part[1023];   // == N_EDGES
    }
}

// ---------------------------------------------------------------------------
// Permute src indices into dst-sorted (CSR) order.
__global__ __launch_bounds__(256) void scatter_idx_kernel(const int* __restrict__ src,
                                                          const int* __restrict__ dst,
                                                          int* __restrict__ cursor,
                                                          int* __restrict__ edge_src) {
    int e = blockIdx.x * 256 + threadIdx.x;
    if (e >= N_EDGES) return;
    int d = dst[e];
    int pos = atomicAdd(&cursor[d], 1);
    edge_src[pos] = src[e];
}

// ---------------------------------------------------------------------------
// Fused neighbor-sum + projection. Block = 256 threads, 8 nodes per block.
// Phase 0: stage W into LDS, skewed row-major Ws[o*128+((k+o)&127)] = W[o][k]
//          (read at (o varies per lane, k uniform) -> bank (k+o)&31, conflict-free)
// Phase 1: each half-wave (32 lanes, float4/lane) sums x rows of its node's
//          CSR neighbor list; result -> hS[node][128] in LDS.
// Phase 2: thread t computes out[n][o] for o = t&127 and 4 nodes; h reads are
//          wave-uniform broadcasts, Ws reads conflict-free via skew.
// ---------------------------------------------------------------------------
#define NPB 8
__global__ __launch_bounds__(256) void agg_gemm_kernel(
    const float4* __restrict__ x4,       // x as [N_NODES][32] float4
    const int* __restrict__ edge_src,
    const int* __restrict__ row_start,
    const float* __restrict__ W,
    const float* __restrict__ b,
    float* __restrict__ out) {
    __shared__ float Ws[D * D];          // 64 KB skewed
    __shared__ float hS[NPB][D];         // 4 KB

    int t = threadIdx.x;

    // ---- stage W (each thread writes 64 elements) ----
    int k0 = t & (D - 1);
    for (int o = (t >> 7); o < D; o += 2) {
        Ws[o * D + ((k0 + o) & (D - 1))] = W[o * D + k0];
    }

    // ---- aggregation: half-wave per node ----
    int hw = t >> 5;                     // 0..7: node slot in block
    int c = t & 31;                      // float4 column
    int n = blockIdx.x * NPB + hw;
    float4 acc = make_float4(0.f, 0.f, 0.f, 0.f);
    if (n < N_NODES) {
        int j = row_start[n];
        int end = row_start[n + 1];
        // unroll 4 for memory-level parallelism on the gathers
        for (; j + 4 <= end; j += 4) {
            int s0 = edge_src[j + 0];
            int s1 = edge_src[j + 1];
            int s2 = edge_src[j + 2];
            int s3 = edge_src[j + 3];
            float4 v0 = x4[s0 * 32 + c];
            float4 v1 = x4[s1 * 32 + c];
            float4 v2 = x4[s2 * 32 + c];
            float4 v3 = x4[s3 * 32 + c];
            acc.x += v0.x + v1.x + v2.x + v3.x;
            acc.y += v0.y + v1.y + v2.y + v3.y;
            acc.z += v0.z + v1.z + v2.z + v3.z;
            acc.w += v0.w + v1.w + v2.w + v3.w;
        }
        for (; j < end; ++j) {
            int s0 = edge_src[j];
            float4 v0 = x4[s0 * 32 + c];
            acc.x += v0.x; acc.y += v0.y; acc.z += v0.z; acc.w += v0.w;
        }
    }
    *(float4*)&hS[hw][c * 4] = acc;
    __syncthreads();

    // ---- projection: out[n][o] = b[o] + sum_k hS[n][k] * W[o][k] ----
    int o = t & (D - 1);
    int g = t >> 7;                      // 0 or 1: node group
    float bo = b[o];
    float accv[4];
    #pragma unroll
    for (int j = 0; j < 4; ++j) accv[j] = bo;

    #pragma unroll 4
    for (int k = 0; k < D; ++k) {
        float w = Ws[o * D + ((k + o) & (D - 1))];
        #pragma unroll
        for (int j = 0; j < 4; ++j) {
            accv[j] += hS[g * 4 + j][k] * w;
        }
    }

    #pragma unroll
    for (int j = 0; j < 4; ++j) {
        int n2 = blockIdx.x * NPB + g * 4 + j;
        if (n2 < N_NODES) out[n2 * D + o] = accv[j];
    }
}

// ---------------------------------------------------------------------------
extern "C" void kernel_launch(void* const* d_in, const int* in_sizes, int n_in,
                              void* d_out, int out_size, void* d_ws, size_t ws_size,
                              hipStream_t stream) {
    const float* x   = (const float*)d_in[0];
    const int*   src = (const int*)  d_in[1];
    const int*   dst = (const int*)  d_in[2];
    const float* W   = (const float*)d_in[3];
    const float* b   = (const float*)d_in[4];
    float* out = (float*)d_out;

    int* wsI      = (int*)d_ws;
    int* edge_src = wsI + WS_EDGE_SRC;
    int* row_start= wsI + WS_ROWSTART;
    int* cursor   = wsI + WS_CURSOR;
    int* counts   = wsI + WS_COUNTS;

    // 1) zero histogram
    zero_counts_kernel<<<(N_NODES + 255) / 256, 256, 0, stream>>>(counts);

    // 2) histogram of dst
    hist_kernel<<<N_EDGES / 256, 256, 0, stream>>>(dst, counts);

    // 3) exclusive scan -> row_start, cursor
    scan_kernel<<<1, 1024, 0, stream>>>(counts, row_start, cursor);

    // 4) permute src into CSR order
    scatter_idx_kernel<<<N_EDGES / 256, 256, 0, stream>>>(src, dst, cursor, edge_src);

    // 5) fused neighbor-sum + projection
    agg_gemm_kernel<<<N_NODES / NPB, 256, 0, stream>>>(
        (const float4*)x, edge_src, row_start, W, b, out);
}

// Round 3
// 215.088 us; speedup vs baseline: 5.5273x; 1.2282x over previous
//
#include <hip/hip_runtime.h>

#define N_NODES 10000
#define N_EDGES 640000
#define D 128

// ws layout (ints): edge_src[640000] | row_start[10001] | cursor[10001] | counts[10000]
#define WS_EDGE_SRC 0
#define WS_ROWSTART 640000
#define WS_CURSOR   650016
#define WS_COUNTS   660032
// total 670032 ints = 2.68 MB (proven to fit: R0 used 5.12 MB ws)

// ---------------------------------------------------------------------------
// Histogram of dst, 4 edges per thread via int4 loads.
__global__ __launch_bounds__(256) void hist_kernel(const int4* __restrict__ dst4,
                                                   int* __restrict__ counts) {
    int i = blockIdx.x * 256 + threadIdx.x;          // 160000 threads exactly
    int4 d = dst4[i];
    atomicAdd(&counts[d.x], 1);
    atomicAdd(&counts[d.y], 1);
    atomicAdd(&counts[d.z], 1);
    atomicAdd(&counts[d.w], 1);
}

// ---------------------------------------------------------------------------
// Single-block exclusive scan over 10000 counts -> row_start[0..10000] + cursor.
__global__ __launch_bounds__(1024) void scan_kernel(const int* __restrict__ counts,
                                                    int* __restrict__ row_start,
                                                    int* __restrict__ cursor) {
    __shared__ int part[1024];
    int t = threadIdx.x;
    int base = t * 10;
    int local[10];
    int s = 0;
    #pragma unroll
    for (int i = 0; i < 10; ++i) {
        int idx = base + i;
        int c = (idx < N_NODES) ? counts[idx] : 0;
        local[i] = s;
        s += c;
    }
    part[t] = s;
    __syncthreads();
    for (int off = 1; off < 1024; off <<= 1) {
        int v = (t >= off) ? part[t - off] : 0;
        __syncthreads();
        part[t] += v;
        __syncthreads();
    }
    int pre = (t > 0) ? part[t - 1] : 0;
    #pragma unroll
    for (int i = 0; i < 10; ++i) {
        int idx = base + i;
        if (idx < N_NODES) {
            int st = pre + local[i];
            row_start[idx] = st;
            cursor[idx] = st;
        }
    }
    if (t == 1023) row_start[N_NODES] = part[1023];
}

// ---------------------------------------------------------------------------
// Permute src into dst-sorted (CSR) order, 4 edges per thread.
__global__ __launch_bounds__(256) void scatter_idx_kernel(const int4* __restrict__ src4,
                                                          const int4* __restrict__ dst4,
                                                          int* __restrict__ cursor,
                                                          int* __restrict__ edge_src) {
    int i = blockIdx.x * 256 + threadIdx.x;
    int4 s = src4[i];
    int4 d = dst4[i];
    edge_src[atomicAdd(&cursor[d.x], 1)] = s.x;
    edge_src[atomicAdd(&cursor[d.y], 1)] = s.y;
    edge_src[atomicAdd(&cursor[d.z], 1)] = s.z;
    edge_src[atomicAdd(&cursor[d.w], 1)] = s.w;
}

// ---------------------------------------------------------------------------
// Aggregation: h[n] = sum_{CSR neighbors} x[s]. Half-wave (32 lanes) per node,
// float4 per lane, unroll 8 for MLP. NO LDS -> occupancy limited only by VGPRs
// (full 32 waves/CU expected). h is written into d_out (overwritten by gemm).
// ---------------------------------------------------------------------------
__global__ __launch_bounds__(256) void agg_kernel(
    const float4* __restrict__ x4,
    const int* __restrict__ edge_src,
    const int* __restrict__ row_start,
    float4* __restrict__ h4) {
    int t = threadIdx.x;
    int hw = t >> 5;
    int c = t & 31;
    int n = blockIdx.x * 8 + hw;
    if (n >= N_NODES) return;

    int j = row_start[n];
    int end = row_start[n + 1];
    float4 acc = make_float4(0.f, 0.f, 0.f, 0.f);

    for (; j + 8 <= end; j += 8) {
        int s[8];
        #pragma unroll
        for (int u = 0; u < 8; ++u) s[u] = edge_src[j + u];
        float4 v[8];
        #pragma unroll
        for (int u = 0; u < 8; ++u) v[u] = x4[s[u] * 32 + c];
        #pragma unroll
        for (int u = 0; u < 8; ++u) {
            acc.x += v[u].x; acc.y += v[u].y; acc.z += v[u].z; acc.w += v[u].w;
        }
    }
    for (; j < end; ++j) {
        float4 v = x4[edge_src[j] * 32 + c];
        acc.x += v.x; acc.y += v.y; acc.z += v.z; acc.w += v.w;
    }
    h4[n * 32 + c] = acc;
}

// ---------------------------------------------------------------------------
// In-place projection on d_out: out[n][o] = b[o] + sum_k h[n][k]*W[o][k].
// Block reads its 32 rows of h into LDS (transposed) BEFORE writing them back.
// Ws skewed: Ws[o*128 + ((k+o)&127)] -> per-k read bank (k+o)&31, 2-way, free.
// hT[k][n]: inner-loop reads are wave-uniform float4 broadcasts.
// ---------------------------------------------------------------------------
#define GNPB 32
__global__ __launch_bounds__(256) void gemm_kernel(
    const float* __restrict__ W,
    const float* __restrict__ b,
    float* __restrict__ out) {
    __shared__ float Ws[D * D];       // 64 KB
    __shared__ float hT[D][GNPB];     // 16 KB, transposed

    int t = threadIdx.x;
    int n0 = blockIdx.x * GNPB;

    // stage W (skewed)
    int k0 = t & (D - 1);
    for (int o = (t >> 7); o < D; o += 2) {
        Ws[o * D + ((k0 + o) & (D - 1))] = W[o * D + k0];
    }

    // stage h rows transposed: idx -> n = idx&31, kq = idx>>5 (float4 along k)
    const float4* h4 = (const float4*)out;
    for (int idx = t; idx < GNPB * 32; idx += 256) {
        int n = idx & 31;
        int kq = idx >> 5;
        float4 v = make_float4(0.f, 0.f, 0.f, 0.f);
        if (n0 + n < N_NODES) v = h4[(n0 + n) * 32 + kq];
        hT[kq * 4 + 0][n] = v.x;
        hT[kq * 4 + 1][n] = v.y;
        hT[kq * 4 + 2][n] = v.z;
        hT[kq * 4 + 3][n] = v.w;
    }
    __syncthreads();

    int o = t & (D - 1);
    int g = t >> 7;                   // 0/1 -> nodes g*16 .. g*16+15
    float bo = b[o];
    float acc[16];
    #pragma unroll
    for (int j = 0; j < 16; ++j) acc[j] = bo;

    for (int k = 0; k < D; ++k) {
        float w = Ws[o * D + ((k + o) & (D - 1))];
        float4 h0 = *(const float4*)&hT[k][g * 16 + 0];
        float4 h1 = *(const float4*)&hT[k][g * 16 + 4];
        float4 h2 = *(const float4*)&hT[k][g * 16 + 8];
        float4 h3 = *(const float4*)&hT[k][g * 16 + 12];
        acc[0]  += h0.x * w; acc[1]  += h0.y * w; acc[2]  += h0.z * w; acc[3]  += h0.w * w;
        acc[4]  += h1.x * w; acc[5]  += h1.y * w; acc[6]  += h1.z * w; acc[7]  += h1.w * w;
        acc[8]  += h2.x * w; acc[9]  += h2.y * w; acc[10] += h2.z * w; acc[11] += h2.w * w;
        acc[12] += h3.x * w; acc[13] += h3.y * w; acc[14] += h3.z * w; acc[15] += h3.w * w;
    }

    #pragma unroll
    for (int j = 0; j < 16; ++j) {
        int n = n0 + g * 16 + j;
        if (n < N_NODES) out[n * D + o] = acc[j];
    }
}

// ---------------------------------------------------------------------------
extern "C" void kernel_launch(void* const* d_in, const int* in_sizes, int n_in,
                              void* d_out, int out_size, void* d_ws, size_t ws_size,
                              hipStream_t stream) {
    const float* x   = (const float*)d_in[0];
    const int*   src = (const int*)  d_in[1];
    const int*   dst = (const int*)  d_in[2];
    const float* W   = (const float*)d_in[3];
    const float* b   = (const float*)d_in[4];
    float* out = (float*)d_out;

    int* wsI      = (int*)d_ws;
    int* edge_src = wsI + WS_EDGE_SRC;
    int* row_start= wsI + WS_ROWSTART;
    int* cursor   = wsI + WS_CURSOR;
    int* counts   = wsI + WS_COUNTS;

    // 1) zero histogram (graph-capturable)
    hipMemsetAsync(counts, 0, N_NODES * sizeof(int), stream);

    // 2) histogram of dst (int4, 4 edges/thread)
    hist_kernel<<<N_EDGES / 1024, 256, 0, stream>>>((const int4*)dst, counts);

    // 3) exclusive scan -> row_start, cursor
    scan_kernel<<<1, 1024, 0, stream>>>(counts, row_start, cursor);

    // 4) permute src into CSR order (int4, 4 edges/thread)
    scatter_idx_kernel<<<N_EDGES / 1024, 256, 0, stream>>>(
        (const int4*)src, (const int4*)dst, cursor, edge_src);

    // 5) aggregate x -> h (stored in d_out)
    agg_kernel<<<N_NODES / 8, 256, 0, stream>>>(
        (const float4*)x, edge_src, row_start, (float4*)out);

    // 6) in-place projection: out = h @ W.T + b
    gemm_kernel<<<(N_NODES + GNPB - 1) / GNPB, 256, 0, stream>>>(W, b, out);
}